// Round 1
// baseline (171.535 us; speedup 1.0000x reference)
//
#include <hip/hip_runtime.h>
#include <stdint.h>

typedef short short8 __attribute__((ext_vector_type(8)));
typedef float floatx4 __attribute__((ext_vector_type(4)));

#define NN 100000   // nodes
#define NE 800000   // edges
#define KF 128      // in_feat (K of node GEMM)
#define PC 256      // P columns: [0:128)=P1+b1 (src half), [128:256)=P2 (dst half)
#define BM 64       // nodes per block in node kernel
#define LDK 136     // padded LDS row stride in shorts (128 + 8): stride 68 dwords -> 2-way bank alias (free)

// fp32 -> bf16 (RNE)
__device__ __forceinline__ unsigned short f2bf(float x) {
  union { float f; unsigned u; } c; c.f = x;
  unsigned u = c.u + 0x7FFFu + ((c.u >> 16) & 1u);
  return (unsigned short)(u >> 16);
}
// bf16 (low/high half of dword) -> fp32
__device__ __forceinline__ float bfl(unsigned u) {
  union { unsigned u; float f; } c; c.u = u << 16; return c.f;
}
__device__ __forceinline__ float bfh(unsigned u) {
  union { unsigned u; float f; } c; c.u = u & 0xFFFF0000u; return c.f;
}

// ---------------------------------------------------------------------------
// Kernel 1: P[n][j] = sum_k feature[n][k] * Wcat[j][k]  (+ b1[j] for j<128)
//   Wcat[j][k] = (j<128) ? W1[j][k] : W1[j-128][128+k]
// MFMA 16x16x32 bf16. Per block: 64 nodes x 256 cols. W staged in 2 halves
// of 128 rows to keep LDS at ~52.7 KB (3 blocks/CU).
// (unchanged this round — isolating the edge-kernel MLP change)
// ---------------------------------------------------------------------------
extern "C" __global__ void __launch_bounds__(256)
node_proj_kernel(const float* __restrict__ feature,
                 const float* __restrict__ W1,
                 const float* __restrict__ b1,
                 unsigned short* __restrict__ P)
{
  __shared__ unsigned short Wl[128 * LDK]; // 34816 B (one 128-row half of Wcat)
  __shared__ unsigned short Al[BM * LDK];  // 17408 B
  __shared__ float b1l[128];

  const int t = threadIdx.x;
  const int nodeBase = blockIdx.x * BM;

  // ---- stage A tile (64 nodes x 128 k, fp32 -> bf16) ----
  #pragma unroll
  for (int it = 0; it < 4; ++it) {
    int c  = t + it * 256;       // chunk of 8 elems, 0..1023
    int nl = c >> 4;             // local node 0..63
    int kc = (c & 15) << 3;      // k offset 0..120
    int node = nodeBase + nl;
    float4 f0 = make_float4(0.f, 0.f, 0.f, 0.f);
    float4 f1 = make_float4(0.f, 0.f, 0.f, 0.f);
    if (node < NN) {
      const float* fp = feature + (size_t)node * KF + kc;
      f0 = ((const float4*)fp)[0];
      f1 = ((const float4*)fp)[1];
    }
    short8 v;
    v[0] = (short)f2bf(f0.x); v[1] = (short)f2bf(f0.y);
    v[2] = (short)f2bf(f0.z); v[3] = (short)f2bf(f0.w);
    v[4] = (short)f2bf(f1.x); v[5] = (short)f2bf(f1.y);
    v[6] = (short)f2bf(f1.z); v[7] = (short)f2bf(f1.w);
    *(short8*)&Al[nl * LDK + kc] = v;
  }
  if (t < 128) b1l[t] = b1[t];

  const int wave = t >> 6;
  const int lane = t & 63;
  const int m16  = lane & 15;
  const int quad = lane >> 4;

  short8 a0, a1, a2, a3;
  bool aLoaded = false;

  for (int half = 0; half < 2; ++half) {
    // ---- stage one 128-row half of Wcat (bf16) ----
    #pragma unroll
    for (int it = 0; it < 8; ++it) {
      int c  = t + it * 256;     // 0..2047
      int jl = c >> 4;           // local row 0..127
      int kc = (c & 15) << 3;
      const float* sp = W1 + jl * 256 + half * 128 + kc;
      float4 f0 = ((const float4*)sp)[0];
      float4 f1 = ((const float4*)sp)[1];
      short8 v;
      v[0] = (short)f2bf(f0.x); v[1] = (short)f2bf(f0.y);
      v[2] = (short)f2bf(f0.z); v[3] = (short)f2bf(f0.w);
      v[4] = (short)f2bf(f1.x); v[5] = (short)f2bf(f1.y);
      v[6] = (short)f2bf(f1.z); v[7] = (short)f2bf(f1.w);
      *(short8*)&Wl[jl * LDK + kc] = v;
    }
    __syncthreads();

    if (!aLoaded) {
      const unsigned short* arow = &Al[(wave * 16 + m16) * LDK + quad * 8];
      a0 = *(const short8*)(arow + 0);
      a1 = *(const short8*)(arow + 32);
      a2 = *(const short8*)(arow + 64);
      a3 = *(const short8*)(arow + 96);
      aLoaded = true;
    }

    #pragma unroll
    for (int nt = 0; nt < 8; ++nt) {
      floatx4 acc = {0.f, 0.f, 0.f, 0.f};
      const unsigned short* wrow = &Wl[(nt * 16 + m16) * LDK + quad * 8];
      acc = __builtin_amdgcn_mfma_f32_16x16x32_bf16(a0, *(const short8*)(wrow +  0), acc, 0, 0, 0);
      acc = __builtin_amdgcn_mfma_f32_16x16x32_bf16(a1, *(const short8*)(wrow + 32), acc, 0, 0, 0);
      acc = __builtin_amdgcn_mfma_f32_16x16x32_bf16(a2, *(const short8*)(wrow + 64), acc, 0, 0, 0);
      acc = __builtin_amdgcn_mfma_f32_16x16x32_bf16(a3, *(const short8*)(wrow + 96), acc, 0, 0, 0);

      int n = half * 128 + nt * 16 + m16;
      float bias = (half == 0) ? b1l[nt * 16 + m16] : 0.f;
      #pragma unroll
      for (int r = 0; r < 4; ++r) {
        int node = nodeBase + wave * 16 + quad * 4 + r;
        if (node < NN) P[(size_t)node * PC + n] = f2bf(acc[r] + bias);
      }
    }
    __syncthreads();  // before restaging Wl for the next half
  }
}

// ---------------------------------------------------------------------------
// Kernel 2: out[e] = b2 + sum_j relu(P[src[e]][j] + P[dst[e]][128+j]) * W2[j]
//
// v2: 4 edges per 16-lane group (64 edges / 256-thread block).
//   - one int4 load each for the 4 src / 4 dst indices (amortizes the first
//     dependent round-trip 4x, replaces redundant per-lane scalar broadcasts)
//   - 8 independent 16B P-row gathers in flight per thread (4x MLP vs v1)
//   - 4 butterfly reductions, then a coalesced float4 store of 4 scores.
// NE = 800000 is divisible by 64, so no tail handling needed.
// ---------------------------------------------------------------------------
__device__ __forceinline__ float dot8(const uint4 u1, const uint4 u2,
                                      const float4 wA, const float4 wB)
{
  float acc = 0.f, x;
  x = fmaxf(bfl(u1.x) + bfl(u2.x), 0.f); acc += x * wA.x;
  x = fmaxf(bfh(u1.x) + bfh(u2.x), 0.f); acc += x * wA.y;
  x = fmaxf(bfl(u1.y) + bfl(u2.y), 0.f); acc += x * wA.z;
  x = fmaxf(bfh(u1.y) + bfh(u2.y), 0.f); acc += x * wA.w;
  x = fmaxf(bfl(u1.z) + bfl(u2.z), 0.f); acc += x * wB.x;
  x = fmaxf(bfh(u1.z) + bfh(u2.z), 0.f); acc += x * wB.y;
  x = fmaxf(bfl(u1.w) + bfl(u2.w), 0.f); acc += x * wB.z;
  x = fmaxf(bfh(u1.w) + bfh(u2.w), 0.f); acc += x * wB.w;
  return acc;
}

extern "C" __global__ void __launch_bounds__(256)
edge_score_kernel(const unsigned short* __restrict__ P,
                  const int* __restrict__ src,
                  const int* __restrict__ dst,
                  const float* __restrict__ W2,
                  const float* __restrict__ b2,
                  float* __restrict__ out)
{
  const int t    = threadIdx.x;
  const int lane = t & 15;
  const int g    = t >> 4;
  const int e0   = blockIdx.x * 64 + g * 4;
  if (e0 >= NE) return;

  // 4 src + 4 dst indices in two 16B loads (same addr across the 16-lane
  // group -> L1 broadcast; distinct across groups).
  const int4 sv = *(const int4*)(src + e0);
  const int4 dv = *(const int4*)(dst + e0);

  const unsigned short* Ps = P + lane * 8;          // src half base (+row)
  const unsigned short* Pd = P + 128 + lane * 8;    // dst half base (+row)

  // 8 independent gathers, all in flight before any use.
  const uint4 A0 = *(const uint4*)(Ps + (size_t)sv.x * PC);
  const uint4 B0 = *(const uint4*)(Pd + (size_t)dv.x * PC);
  const uint4 A1 = *(const uint4*)(Ps + (size_t)sv.y * PC);
  const uint4 B1 = *(const uint4*)(Pd + (size_t)dv.y * PC);
  const uint4 A2 = *(const uint4*)(Ps + (size_t)sv.z * PC);
  const uint4 B2 = *(const uint4*)(Pd + (size_t)dv.z * PC);
  const uint4 A3 = *(const uint4*)(Ps + (size_t)sv.w * PC);
  const uint4 B3 = *(const uint4*)(Pd + (size_t)dv.w * PC);

  const float4 wA = *(const float4*)(W2 + lane * 8);
  const float4 wB = *(const float4*)(W2 + lane * 8 + 4);

  float r0 = dot8(A0, B0, wA, wB);
  float r1 = dot8(A1, B1, wA, wB);
  float r2 = dot8(A2, B2, wA, wB);
  float r3 = dot8(A3, B3, wA, wB);

  // butterfly within each 16-lane group
  r0 += __shfl_xor(r0, 8); r1 += __shfl_xor(r1, 8);
  r2 += __shfl_xor(r2, 8); r3 += __shfl_xor(r3, 8);
  r0 += __shfl_xor(r0, 4); r1 += __shfl_xor(r1, 4);
  r2 += __shfl_xor(r2, 4); r3 += __shfl_xor(r3, 4);
  r0 += __shfl_xor(r0, 2); r1 += __shfl_xor(r1, 2);
  r2 += __shfl_xor(r2, 2); r3 += __shfl_xor(r3, 2);
  r0 += __shfl_xor(r0, 1); r1 += __shfl_xor(r1, 1);
  r2 += __shfl_xor(r2, 1); r3 += __shfl_xor(r3, 1);

  if (lane == 0) {
    const float bb = b2[0];
    float4 o;
    o.x = r0 + bb; o.y = r1 + bb; o.z = r2 + bb; o.w = r3 + bb;
    *(float4*)(out + e0) = o;   // e0 % 4 == 0 -> 16B aligned, coalesced
  }
}

extern "C" void kernel_launch(void* const* d_in, const int* in_sizes, int n_in,
                              void* d_out, int out_size, void* d_ws, size_t ws_size,
                              hipStream_t stream)
{
  const float* feature = (const float*)d_in[0];
  const int*   src     = (const int*)d_in[1];
  const int*   dst     = (const int*)d_in[2];
  const float* W1      = (const float*)d_in[3];
  const float* b1      = (const float*)d_in[4];
  const float* W2      = (const float*)d_in[5];
  const float* b2      = (const float*)d_in[6];
  float* out = (float*)d_out;
  unsigned short* P = (unsigned short*)d_ws;  // [NN][256] bf16, 51.2 MB

  dim3 grid1((NN + BM - 1) / BM);   // 1563 blocks
  node_proj_kernel<<<grid1, 256, 0, stream>>>(feature, W1, b1, P);

  dim3 grid2((NE + 63) / 64);       // 12500 blocks, 64 edges/block
  edge_score_kernel<<<grid2, 256, 0, stream>>>(P, src, dst, W2, b2, out);
}

// Round 2
// 170.388 us; speedup vs baseline: 1.0067x; 1.0067x over previous
//
#include <hip/hip_runtime.h>
#include <stdint.h>

typedef short short8 __attribute__((ext_vector_type(8)));
typedef float floatx4 __attribute__((ext_vector_type(4)));

#define NN 100000   // nodes
#define NE 800000   // edges
#define KF 128      // in_feat (K of node GEMM)
#define PC 256      // P columns: [0:128)=P1+b1 (src half), [128:256)=P2 (dst half)
#define BM 64       // nodes per block in node kernel
#define LDK 136     // padded LDS row stride in shorts for the A tile (free 2-way alias)

// fp32 -> bf16 (RNE)
__device__ __forceinline__ unsigned short f2bf(float x) {
  union { float f; unsigned u; } c; c.f = x;
  unsigned u = c.u + 0x7FFFu + ((c.u >> 16) & 1u);
  return (unsigned short)(u >> 16);
}
// bf16 (low/high half of dword) -> fp32
__device__ __forceinline__ float bfl(unsigned u) {
  union { unsigned u; float f; } c; c.u = u << 16; return c.f;
}
__device__ __forceinline__ float bfh(unsigned u) {
  union { unsigned u; float f; } c; c.u = u & 0xFFFF0000u; return c.f;
}

// ---------------------------------------------------------------------------
// Kernel 0: one-time W1 (fp32 [128][256]) -> Wcat bf16, concatenated layout,
// PRE-SWIZZLED so node_proj can stage it with linear global_load_lds and read
// B-fragments through the same XOR (both-sides-or-neither, m173 pattern).
//   Wcat[j][k] = (j<128) ? W1[j][k] : W1[j-128][128+k],  j in [0,256), k in [0,128)
// Element (half h = j>>7, local row jl = j&127, col k) goes to byte offset
//   h*32768 + ((jl*256 + 2k) ^ ((jl&7)<<4))
// Output lives in d_out (3.2 MB >> 64 KB), which edge_score overwrites later.
// ---------------------------------------------------------------------------
extern "C" __global__ void __launch_bounds__(256)
wcat_prep_kernel(const float* __restrict__ W1, unsigned short* __restrict__ Wcatb)
{
  const int idx = blockIdx.x * 256 + threadIdx.x;  // 4096 threads, 8 elems each
  const int j  = idx >> 4;          // Wcat row 0..255
  const int k8 = (idx & 15) << 3;   // k chunk start 0..120

  const int h  = j >> 7;
  const int jl = j & 127;
  const float* sp = W1 + (size_t)jl * 256 + h * 128 + k8;
  const float4 f0 = ((const float4*)sp)[0];
  const float4 f1 = ((const float4*)sp)[1];

  short8 v;
  v[0] = (short)f2bf(f0.x); v[1] = (short)f2bf(f0.y);
  v[2] = (short)f2bf(f0.z); v[3] = (short)f2bf(f0.w);
  v[4] = (short)f2bf(f1.x); v[5] = (short)f2bf(f1.y);
  v[6] = (short)f2bf(f1.z); v[7] = (short)f2bf(f1.w);

  const unsigned lin = (unsigned)jl * 256u + (unsigned)k8 * 2u;  // byte offset in half
  const unsigned swz = lin ^ ((unsigned)(jl & 7) << 4);          // XOR bits 4..6, keeps 16B align
  *(short8*)((char*)Wcatb + h * 32768 + swz) = v;
}

// ---------------------------------------------------------------------------
// Kernel 1: P[n][j] = sum_k feature[n][k] * Wcat[j][k]  (+ b1[j] for j<128)
// v3: W staged via async global_load_lds (width 16) from the pre-converted,
// pre-swizzled bf16 buffer — no per-block fp32 reads, no per-block VALU
// conversion of W (was ~51M redundant f2bf ops kernel-wide).
// LDS: Wl 32 KB (one 128-row half, swizzled) + Al 17 KB -> ~50 KB, 3 blocks/CU.
// ---------------------------------------------------------------------------
extern "C" __global__ void __launch_bounds__(256)
node_proj_kernel(const float* __restrict__ feature,
                 const unsigned short* __restrict__ Wcatb,
                 const float* __restrict__ b1,
                 unsigned short* __restrict__ P)
{
  __shared__ unsigned short Wl[128 * 128]; // 32768 B, swizzled rows of one half
  __shared__ unsigned short Al[BM * LDK];  // 17408 B, padded (read-side friendly)
  __shared__ float b1l[128];

  const int t = threadIdx.x;
  const int nodeBase = blockIdx.x * BM;

  // ---- issue async W staging for half 0 FIRST (DMA overlaps A conversion) --
  #pragma unroll
  for (int it = 0; it < 8; ++it) {
    int c = t + it * 256;  // 0..2047 chunks of 16 B
    __builtin_amdgcn_global_load_lds(
        (const __attribute__((address_space(1))) void*)((const char*)Wcatb + c * 16),
        (__attribute__((address_space(3))) void*)((char*)Wl + c * 16),
        16, 0, 0);
  }

  // ---- stage A tile (64 nodes x 128 k, fp32 -> bf16) ----
  #pragma unroll
  for (int it = 0; it < 4; ++it) {
    int c  = t + it * 256;       // chunk of 8 elems, 0..1023
    int nl = c >> 4;             // local node 0..63
    int kc = (c & 15) << 3;      // k offset 0..120
    int node = nodeBase + nl;
    float4 f0 = make_float4(0.f, 0.f, 0.f, 0.f);
    float4 f1 = make_float4(0.f, 0.f, 0.f, 0.f);
    if (node < NN) {
      const float* fp = feature + (size_t)node * KF + kc;
      f0 = ((const float4*)fp)[0];
      f1 = ((const float4*)fp)[1];
    }
    short8 v;
    v[0] = (short)f2bf(f0.x); v[1] = (short)f2bf(f0.y);
    v[2] = (short)f2bf(f0.z); v[3] = (short)f2bf(f0.w);
    v[4] = (short)f2bf(f1.x); v[5] = (short)f2bf(f1.y);
    v[6] = (short)f2bf(f1.z); v[7] = (short)f2bf(f1.w);
    *(short8*)&Al[nl * LDK + kc] = v;
  }
  if (t < 128) b1l[t] = b1[t];

  const int wave = t >> 6;
  const int lane = t & 63;
  const int m16  = lane & 15;
  const int quad = lane >> 4;

  short8 a0, a1, a2, a3;
  bool aLoaded = false;

  for (int half = 0; half < 2; ++half) {
    __syncthreads();  // drains vmcnt: W half + (first iter) A writes visible

    if (!aLoaded) {
      const unsigned short* arow = &Al[(wave * 16 + m16) * LDK + quad * 8];
      a0 = *(const short8*)(arow + 0);
      a1 = *(const short8*)(arow + 32);
      a2 = *(const short8*)(arow + 64);
      a3 = *(const short8*)(arow + 96);
      aLoaded = true;
    }

    #pragma unroll
    for (int nt = 0; nt < 8; ++nt) {
      floatx4 acc = {0.f, 0.f, 0.f, 0.f};
      const int j = nt * 16 + m16;                  // W row within this half
      const unsigned base = (unsigned)j * 256u + (unsigned)quad * 16u;
      const unsigned msk  = (unsigned)(j & 7) << 4;
      const char* WlB = (const char*)Wl;
      acc = __builtin_amdgcn_mfma_f32_16x16x32_bf16(a0, *(const short8*)(WlB + ((base +   0u) ^ msk)), acc, 0, 0, 0);
      acc = __builtin_amdgcn_mfma_f32_16x16x32_bf16(a1, *(const short8*)(WlB + ((base +  64u) ^ msk)), acc, 0, 0, 0);
      acc = __builtin_amdgcn_mfma_f32_16x16x32_bf16(a2, *(const short8*)(WlB + ((base + 128u) ^ msk)), acc, 0, 0, 0);
      acc = __builtin_amdgcn_mfma_f32_16x16x32_bf16(a3, *(const short8*)(WlB + ((base + 192u) ^ msk)), acc, 0, 0, 0);

      const int n = half * 128 + j;
      const float bias = (half == 0) ? b1l[j] : 0.f;
      #pragma unroll
      for (int r = 0; r < 4; ++r) {
        int node = nodeBase + wave * 16 + quad * 4 + r;
        if (node < NN) P[(size_t)node * PC + n] = f2bf(acc[r] + bias);
      }
    }

    if (half == 0) {
      __syncthreads();  // everyone done reading Wl half 0 before restage
      #pragma unroll
      for (int it = 0; it < 8; ++it) {
        int c = t + it * 256;
        __builtin_amdgcn_global_load_lds(
            (const __attribute__((address_space(1))) void*)((const char*)Wcatb + 32768 + c * 16),
            (__attribute__((address_space(3))) void*)((char*)Wl + c * 16),
            16, 0, 0);
      }
    }
  }
}

// ---------------------------------------------------------------------------
// Kernel 2: out[e] = b2 + sum_j relu(P[src[e]][j] + P[dst[e]][128+j]) * W2[j]
// (unchanged from v2 — control group; EA-traffic-bound at ~3.5 TB/s)
// ---------------------------------------------------------------------------
__device__ __forceinline__ float dot8(const uint4 u1, const uint4 u2,
                                      const float4 wA, const float4 wB)
{
  float acc = 0.f, x;
  x = fmaxf(bfl(u1.x) + bfl(u2.x), 0.f); acc += x * wA.x;
  x = fmaxf(bfh(u1.x) + bfh(u2.x), 0.f); acc += x * wA.y;
  x = fmaxf(bfl(u1.y) + bfl(u2.y), 0.f); acc += x * wA.z;
  x = fmaxf(bfh(u1.y) + bfh(u2.y), 0.f); acc += x * wA.w;
  x = fmaxf(bfl(u1.z) + bfl(u2.z), 0.f); acc += x * wB.x;
  x = fmaxf(bfh(u1.z) + bfh(u2.z), 0.f); acc += x * wB.y;
  x = fmaxf(bfl(u1.w) + bfl(u2.w), 0.f); acc += x * wB.z;
  x = fmaxf(bfh(u1.w) + bfh(u2.w), 0.f); acc += x * wB.w;
  return acc;
}

extern "C" __global__ void __launch_bounds__(256)
edge_score_kernel(const unsigned short* __restrict__ P,
                  const int* __restrict__ src,
                  const int* __restrict__ dst,
                  const float* __restrict__ W2,
                  const float* __restrict__ b2,
                  float* __restrict__ out)
{
  const int t    = threadIdx.x;
  const int lane = t & 15;
  const int g    = t >> 4;
  const int e0   = blockIdx.x * 64 + g * 4;
  if (e0 >= NE) return;

  const int4 sv = *(const int4*)(src + e0);
  const int4 dv = *(const int4*)(dst + e0);

  const unsigned short* Ps = P + lane * 8;          // src half base (+row)
  const unsigned short* Pd = P + 128 + lane * 8;    // dst half base (+row)

  // 8 independent gathers, all in flight before any use.
  const uint4 A0 = *(const uint4*)(Ps + (size_t)sv.x * PC);
  const uint4 B0 = *(const uint4*)(Pd + (size_t)dv.x * PC);
  const uint4 A1 = *(const uint4*)(Ps + (size_t)sv.y * PC);
  const uint4 B1 = *(const uint4*)(Pd + (size_t)dv.y * PC);
  const uint4 A2 = *(const uint4*)(Ps + (size_t)sv.z * PC);
  const uint4 B2 = *(const uint4*)(Pd + (size_t)dv.z * PC);
  const uint4 A3 = *(const uint4*)(Ps + (size_t)sv.w * PC);
  const uint4 B3 = *(const uint4*)(Pd + (size_t)dv.w * PC);

  const float4 wA = *(const float4*)(W2 + lane * 8);
  const float4 wB = *(const float4*)(W2 + lane * 8 + 4);

  float r0 = dot8(A0, B0, wA, wB);
  float r1 = dot8(A1, B1, wA, wB);
  float r2 = dot8(A2, B2, wA, wB);
  float r3 = dot8(A3, B3, wA, wB);

  r0 += __shfl_xor(r0, 8); r1 += __shfl_xor(r1, 8);
  r2 += __shfl_xor(r2, 8); r3 += __shfl_xor(r3, 8);
  r0 += __shfl_xor(r0, 4); r1 += __shfl_xor(r1, 4);
  r2 += __shfl_xor(r2, 4); r3 += __shfl_xor(r3, 4);
  r0 += __shfl_xor(r0, 2); r1 += __shfl_xor(r1, 2);
  r2 += __shfl_xor(r2, 2); r3 += __shfl_xor(r3, 2);
  r0 += __shfl_xor(r0, 1); r1 += __shfl_xor(r1, 1);
  r2 += __shfl_xor(r2, 1); r3 += __shfl_xor(r3, 1);

  if (lane == 0) {
    const float bb = b2[0];
    float4 o;
    o.x = r0 + bb; o.y = r1 + bb; o.z = r2 + bb; o.w = r3 + bb;
    *(float4*)(out + e0) = o;
  }
}

extern "C" void kernel_launch(void* const* d_in, const int* in_sizes, int n_in,
                              void* d_out, int out_size, void* d_ws, size_t ws_size,
                              hipStream_t stream)
{
  const float* feature = (const float*)d_in[0];
  const int*   src     = (const int*)d_in[1];
  const int*   dst     = (const int*)d_in[2];
  const float* W1      = (const float*)d_in[3];
  const float* b1      = (const float*)d_in[4];
  const float* W2      = (const float*)d_in[5];
  const float* b2      = (const float*)d_in[6];
  float* out = (float*)d_out;
  unsigned short* P = (unsigned short*)d_ws;       // [NN][256] bf16, 51.2 MB
  unsigned short* Wcatb = (unsigned short*)d_out;  // 64 KB scratch inside out
                                                   // (read before out is written)

  dim3 gridW(16);
  wcat_prep_kernel<<<gridW, 256, 0, stream>>>(W1, Wcatb);

  dim3 grid1((NN + BM - 1) / BM);   // 1563 blocks
  node_proj_kernel<<<grid1, 256, 0, stream>>>(feature, Wcatb, b1, P);

  dim3 grid2((NE + 63) / 64);       // 12500 blocks, 64 edges/block
  edge_score_kernel<<<grid2, 256, 0, stream>>>(P, src, dst, W2, b2, out);
}

// Round 4
// 144.450 us; speedup vs baseline: 1.1875x; 1.1796x over previous
//
#include <hip/hip_runtime.h>
#include <stdint.h>

typedef short short8 __attribute__((ext_vector_type(8)));
typedef float floatx4 __attribute__((ext_vector_type(4)));

#define NN 100000   // nodes
#define NE 800000   // edges
#define KF 128      // in_feat (K of node GEMM)
#define PC 256      // P row stride in BYTES: [0:128)=src half int8, [128:256)=dst half int8
#define BM 64       // nodes per block in node kernel
#define LDK 136     // padded LDS row stride in shorts for the A tile (free 2-way alias)

// fp32 -> bf16 (RNE)
__device__ __forceinline__ unsigned short f2bf(float x) {
  union { float f; unsigned u; } c; c.f = x;
  unsigned u = c.u + 0x7FFFu + ((c.u >> 16) & 1u);
  return (unsigned short)(u >> 16);
}
// signed byte k of u -> float
__device__ __forceinline__ float sb8(unsigned u, int k) {
  return (float)(signed char)((u >> (8 * k)) & 0xffu);
}

// ---------------------------------------------------------------------------
// Kernel 0: one-time W1 (fp32 [128][256]) -> Wcat bf16, concatenated layout,
// PRE-SWIZZLED for linear global_load_lds staging + XOR'd B-fragment reads.
//   Wcat[j][k] = (j<128) ? W1[j][k] : W1[j-128][128+k]
// Output in d_out (read by node_proj before edge_score overwrites d_out).
// ---------------------------------------------------------------------------
extern "C" __global__ void __launch_bounds__(256)
wcat_prep_kernel(const float* __restrict__ W1, unsigned short* __restrict__ Wcatb)
{
  const int idx = blockIdx.x * 256 + threadIdx.x;  // 4096 threads, 8 elems each
  const int j  = idx >> 4;          // Wcat row 0..255
  const int k8 = (idx & 15) << 3;   // k chunk start 0..120

  const int h  = j >> 7;
  const int jl = j & 127;
  const float* sp = W1 + (size_t)jl * 256 + h * 128 + k8;
  const float4 f0 = ((const float4*)sp)[0];
  const float4 f1 = ((const float4*)sp)[1];

  short8 v;
  v[0] = (short)f2bf(f0.x); v[1] = (short)f2bf(f0.y);
  v[2] = (short)f2bf(f0.z); v[3] = (short)f2bf(f0.w);
  v[4] = (short)f2bf(f1.x); v[5] = (short)f2bf(f1.y);
  v[6] = (short)f2bf(f1.z); v[7] = (short)f2bf(f1.w);

  const unsigned lin = (unsigned)jl * 256u + (unsigned)k8 * 2u;  // byte offset in half
  const unsigned swz = lin ^ ((unsigned)(jl & 7) << 4);          // XOR bits 4..6
  *(short8*)((char*)Wcatb + h * 32768 + swz) = v;
}

// ---------------------------------------------------------------------------
// Kernel 1: P[n][j] = int8 round( val / step_n ),  step_n = rowmax/127 per
// (node, half);  val = sum_k feature[n][k]*Wcat[j][k] (+ b1[j] for half 0).
// Sc[n][h] holds step (dequant factor). Same MFMA + async-W-staging body as
// round 2; epilogue buffers the 8 col-tiles, reduces rowmax across the
// 16-lane m16 group, then quantizes.
// ---------------------------------------------------------------------------
extern "C" __global__ void __launch_bounds__(256)
node_proj_kernel(const float* __restrict__ feature,
                 const unsigned short* __restrict__ Wcatb,
                 const float* __restrict__ b1,
                 signed char* __restrict__ P,
                 float* __restrict__ Sc)
{
  __shared__ unsigned short Wl[128 * 128]; // 32768 B, swizzled rows of one half
  __shared__ unsigned short Al[BM * LDK];  // 17408 B, padded
  __shared__ float b1l[128];

  const int t = threadIdx.x;
  const int nodeBase = blockIdx.x * BM;

  // ---- issue async W staging for half 0 FIRST (DMA overlaps A conversion) --
  #pragma unroll
  for (int it = 0; it < 8; ++it) {
    int c = t + it * 256;  // 0..2047 chunks of 16 B
    __builtin_amdgcn_global_load_lds(
        (const __attribute__((address_space(1))) void*)((const char*)Wcatb + c * 16),
        (__attribute__((address_space(3))) void*)((char*)Wl + c * 16),
        16, 0, 0);
  }

  // ---- stage A tile (64 nodes x 128 k, fp32 -> bf16) ----
  #pragma unroll
  for (int it = 0; it < 4; ++it) {
    int c  = t + it * 256;       // chunk of 8 elems, 0..1023
    int nl = c >> 4;             // local node 0..63
    int kc = (c & 15) << 3;      // k offset 0..120
    int node = nodeBase + nl;
    float4 f0 = make_float4(0.f, 0.f, 0.f, 0.f);
    float4 f1 = make_float4(0.f, 0.f, 0.f, 0.f);
    if (node < NN) {
      const float* fp = feature + (size_t)node * KF + kc;
      f0 = ((const float4*)fp)[0];
      f1 = ((const float4*)fp)[1];
    }
    short8 v;
    v[0] = (short)f2bf(f0.x); v[1] = (short)f2bf(f0.y);
    v[2] = (short)f2bf(f0.z); v[3] = (short)f2bf(f0.w);
    v[4] = (short)f2bf(f1.x); v[5] = (short)f2bf(f1.y);
    v[6] = (short)f2bf(f1.z); v[7] = (short)f2bf(f1.w);
    *(short8*)&Al[nl * LDK + kc] = v;
  }
  if (t < 128) b1l[t] = b1[t];

  const int wave = t >> 6;
  const int lane = t & 63;
  const int m16  = lane & 15;
  const int quad = lane >> 4;

  short8 a0, a1, a2, a3;
  bool aLoaded = false;

  for (int half = 0; half < 2; ++half) {
    __syncthreads();  // drains vmcnt: W half + (first iter) A writes visible

    if (!aLoaded) {
      const unsigned short* arow = &Al[(wave * 16 + m16) * LDK + quad * 8];
      a0 = *(const short8*)(arow + 0);
      a1 = *(const short8*)(arow + 32);
      a2 = *(const short8*)(arow + 64);
      a3 = *(const short8*)(arow + 96);
      aLoaded = true;
    }

    floatx4 arr[8];  // statically indexed via unrolled loops (no scratch)

    #pragma unroll
    for (int nt = 0; nt < 8; ++nt) {
      floatx4 acc = {0.f, 0.f, 0.f, 0.f};
      const int j = nt * 16 + m16;                  // col within this half
      const unsigned base = (unsigned)j * 256u + (unsigned)quad * 16u;
      const unsigned msk  = (unsigned)(j & 7) << 4;
      const char* WlB = (const char*)Wl;
      acc = __builtin_amdgcn_mfma_f32_16x16x32_bf16(a0, *(const short8*)(WlB + ((base +   0u) ^ msk)), acc, 0, 0, 0);
      acc = __builtin_amdgcn_mfma_f32_16x16x32_bf16(a1, *(const short8*)(WlB + ((base +  64u) ^ msk)), acc, 0, 0, 0);
      acc = __builtin_amdgcn_mfma_f32_16x16x32_bf16(a2, *(const short8*)(WlB + ((base + 128u) ^ msk)), acc, 0, 0, 0);
      acc = __builtin_amdgcn_mfma_f32_16x16x32_bf16(a3, *(const short8*)(WlB + ((base + 192u) ^ msk)), acc, 0, 0, 0);
      if (half == 0) {
        const float bias = b1l[j];
        acc[0] += bias; acc[1] += bias; acc[2] += bias; acc[3] += bias;
      }
      arr[nt] = acc;
    }

    // ---- per-row (node, half) max over the 128 cols: 8 local + 16 lanes ----
    float mx0 = 0.f, mx1 = 0.f, mx2 = 0.f, mx3 = 0.f;
    #pragma unroll
    for (int nt = 0; nt < 8; ++nt) {
      mx0 = fmaxf(mx0, fabsf(arr[nt][0]));
      mx1 = fmaxf(mx1, fabsf(arr[nt][1]));
      mx2 = fmaxf(mx2, fabsf(arr[nt][2]));
      mx3 = fmaxf(mx3, fabsf(arr[nt][3]));
    }
    #pragma unroll
    for (int d_ = 1; d_ <= 8; d_ <<= 1) {
      mx0 = fmaxf(mx0, __shfl_xor(mx0, d_));
      mx1 = fmaxf(mx1, __shfl_xor(mx1, d_));
      mx2 = fmaxf(mx2, __shfl_xor(mx2, d_));
      mx3 = fmaxf(mx3, __shfl_xor(mx3, d_));
    }
    const float inv0 = 127.f / fmaxf(mx0, 1e-30f);
    const float inv1 = 127.f / fmaxf(mx1, 1e-30f);
    const float inv2 = 127.f / fmaxf(mx2, 1e-30f);
    const float inv3 = 127.f / fmaxf(mx3, 1e-30f);

    const int n0 = nodeBase + wave * 16 + quad * 4;
    if (m16 == 0) {
      if (n0 + 0 < NN) Sc[(size_t)(n0 + 0) * 2 + half] = mx0 * (1.f / 127.f);
      if (n0 + 1 < NN) Sc[(size_t)(n0 + 1) * 2 + half] = mx1 * (1.f / 127.f);
      if (n0 + 2 < NN) Sc[(size_t)(n0 + 2) * 2 + half] = mx2 * (1.f / 127.f);
      if (n0 + 3 < NN) Sc[(size_t)(n0 + 3) * 2 + half] = mx3 * (1.f / 127.f);
    }

    #pragma unroll
    for (int nt = 0; nt < 8; ++nt) {
      const int off = half * 128 + nt * 16 + m16;
      if (n0 + 0 < NN) P[(size_t)(n0 + 0) * PC + off] = (signed char)(int)rintf(arr[nt][0] * inv0);
      if (n0 + 1 < NN) P[(size_t)(n0 + 1) * PC + off] = (signed char)(int)rintf(arr[nt][1] * inv1);
      if (n0 + 2 < NN) P[(size_t)(n0 + 2) * PC + off] = (signed char)(int)rintf(arr[nt][2] * inv2);
      if (n0 + 3 < NN) P[(size_t)(n0 + 3) * PC + off] = (signed char)(int)rintf(arr[nt][3] * inv3);
    }

    if (half == 0) {
      __syncthreads();  // everyone done reading Wl half 0 before restage
      #pragma unroll
      for (int it = 0; it < 8; ++it) {
        int c = t + it * 256;
        __builtin_amdgcn_global_load_lds(
            (const __attribute__((address_space(1))) void*)((const char*)Wcatb + 32768 + c * 16),
            (__attribute__((address_space(3))) void*)((char*)Wl + c * 16),
            16, 0, 0);
      }
    }
  }
}

// ---------------------------------------------------------------------------
// Kernel 2: out[e] = b2 + sum_j relu(q1[j]*ss + q2[j]*sd) * W2[j]
// int8 P: each row-half is ONE aligned 128-B line (was two). 16-lane group
// handles 4 edges; per edge each lane loads 8 B src + 8 B dst. Scales are
// uniform 4-B broadcast loads from the L2-resident Sc array.
// ---------------------------------------------------------------------------
__device__ __forceinline__ float dot8i8(const uint2 a, const uint2 b,
                                        const float sa, const float sb,
                                        const float* __restrict__ w)
{
  float acc = 0.f, x;
  x = fmaxf(fmaf(sb8(a.x, 0), sa, sb8(b.x, 0) * sb), 0.f); acc = fmaf(x, w[0], acc);
  x = fmaxf(fmaf(sb8(a.x, 1), sa, sb8(b.x, 1) * sb), 0.f); acc = fmaf(x, w[1], acc);
  x = fmaxf(fmaf(sb8(a.x, 2), sa, sb8(b.x, 2) * sb), 0.f); acc = fmaf(x, w[2], acc);
  x = fmaxf(fmaf(sb8(a.x, 3), sa, sb8(b.x, 3) * sb), 0.f); acc = fmaf(x, w[3], acc);
  x = fmaxf(fmaf(sb8(a.y, 0), sa, sb8(b.y, 0) * sb), 0.f); acc = fmaf(x, w[4], acc);
  x = fmaxf(fmaf(sb8(a.y, 1), sa, sb8(b.y, 1) * sb), 0.f); acc = fmaf(x, w[5], acc);
  x = fmaxf(fmaf(sb8(a.y, 2), sa, sb8(b.y, 2) * sb), 0.f); acc = fmaf(x, w[6], acc);
  x = fmaxf(fmaf(sb8(a.y, 3), sa, sb8(b.y, 3) * sb), 0.f); acc = fmaf(x, w[7], acc);
  return acc;
}

extern "C" __global__ void __launch_bounds__(256)
edge_score_kernel(const signed char* __restrict__ P,
                  const float* __restrict__ Sc,
                  const int* __restrict__ src,
                  const int* __restrict__ dst,
                  const float* __restrict__ W2,
                  const float* __restrict__ b2,
                  float* __restrict__ out)
{
  const int t    = threadIdx.x;
  const int lane = t & 15;
  const int g    = t >> 4;
  const int e0   = blockIdx.x * 64 + g * 4;
  if (e0 >= NE) return;

  const int4 sv = *(const int4*)(src + e0);
  const int4 dv = *(const int4*)(dst + e0);

  const signed char* Ps = P + lane * 8;          // src half base (+row)
  const signed char* Pd = P + 128 + lane * 8;    // dst half base (+row)

  // 8 independent row gathers in flight (each row-half = 1 cache line).
  const uint2 A0 = *(const uint2*)(Ps + (size_t)sv.x * PC);
  const uint2 B0 = *(const uint2*)(Pd + (size_t)dv.x * PC);
  const uint2 A1 = *(const uint2*)(Ps + (size_t)sv.y * PC);
  const uint2 B1 = *(const uint2*)(Pd + (size_t)dv.y * PC);
  const uint2 A2 = *(const uint2*)(Ps + (size_t)sv.z * PC);
  const uint2 B2 = *(const uint2*)(Pd + (size_t)dv.z * PC);
  const uint2 A3 = *(const uint2*)(Ps + (size_t)sv.w * PC);
  const uint2 B3 = *(const uint2*)(Pd + (size_t)dv.w * PC);

  // per-edge dequant steps (uniform across the 16-lane group -> broadcast)
  const float sA0 = Sc[(size_t)sv.x * 2];
  const float sB0 = Sc[(size_t)dv.x * 2 + 1];
  const float sA1 = Sc[(size_t)sv.y * 2];
  const float sB1 = Sc[(size_t)dv.y * 2 + 1];
  const float sA2 = Sc[(size_t)sv.z * 2];
  const float sB2 = Sc[(size_t)dv.z * 2 + 1];
  const float sA3 = Sc[(size_t)sv.w * 2];
  const float sB3 = Sc[(size_t)dv.w * 2 + 1];

  float w[8];
  {
    const float4 wA = *(const float4*)(W2 + lane * 8);
    const float4 wB = *(const float4*)(W2 + lane * 8 + 4);
    w[0] = wA.x; w[1] = wA.y; w[2] = wA.z; w[3] = wA.w;
    w[4] = wB.x; w[5] = wB.y; w[6] = wB.z; w[7] = wB.w;
  }

  float r0 = dot8i8(A0, B0, sA0, sB0, w);
  float r1 = dot8i8(A1, B1, sA1, sB1, w);
  float r2 = dot8i8(A2, B2, sA2, sB2, w);
  float r3 = dot8i8(A3, B3, sA3, sB3, w);

  r0 += __shfl_xor(r0, 8); r1 += __shfl_xor(r1, 8);
  r2 += __shfl_xor(r2, 8); r3 += __shfl_xor(r3, 8);
  r0 += __shfl_xor(r0, 4); r1 += __shfl_xor(r1, 4);
  r2 += __shfl_xor(r2, 4); r3 += __shfl_xor(r3, 4);
  r0 += __shfl_xor(r0, 2); r1 += __shfl_xor(r1, 2);
  r2 += __shfl_xor(r2, 2); r3 += __shfl_xor(r3, 2);
  r0 += __shfl_xor(r0, 1); r1 += __shfl_xor(r1, 1);
  r2 += __shfl_xor(r2, 1); r3 += __shfl_xor(r3, 1);

  if (lane == 0) {
    const float bb = b2[0];
    float4 o;
    o.x = r0 + bb; o.y = r1 + bb; o.z = r2 + bb; o.w = r3 + bb;
    *(float4*)(out + e0) = o;
  }
}

extern "C" void kernel_launch(void* const* d_in, const int* in_sizes, int n_in,
                              void* d_out, int out_size, void* d_ws, size_t ws_size,
                              hipStream_t stream)
{
  const float* feature = (const float*)d_in[0];
  const int*   src     = (const int*)d_in[1];
  const int*   dst     = (const int*)d_in[2];
  const float* W1      = (const float*)d_in[3];
  const float* b1      = (const float*)d_in[4];
  const float* W2      = (const float*)d_in[5];
  const float* b2      = (const float*)d_in[6];
  float* out = (float*)d_out;
  signed char* P = (signed char*)d_ws;                     // [NN][256] int8, 25.6 MB
  float* Sc = (float*)((char*)d_ws + (size_t)NN * PC);     // [NN][2] steps, 0.8 MB
  unsigned short* Wcatb = (unsigned short*)d_out;          // 64 KB scratch inside out
                                                           // (read before out written)

  dim3 gridW(16);
  wcat_prep_kernel<<<gridW, 256, 0, stream>>>(W1, Wcatb);

  dim3 grid1((NN + BM - 1) / BM);   // 1563 blocks
  node_proj_kernel<<<grid1, 256, 0, stream>>>(feature, Wcatb, b1, P, Sc);

  dim3 grid2((NE + 63) / 64);       // 12500 blocks, 64 edges/block
  edge_score_kernel<<<grid2, 256, 0, stream>>>(P, Sc, src, dst, W2, b2, out);
}